// Round 11
// baseline (482.751 us; speedup 1.0000x reference)
//
#include <hip/hip_runtime.h>
#include <hip/hip_fp16.h>

#define N_NODES 50000
#define N_EDGES 800000
#define D 128
#define ND (N_NODES * D)
#define BN_EPS 1e-5f
#define LO_SCALE 2048.0f
#define LO_INV (1.0f / 2048.0f)

typedef _Float16 f16x8 __attribute__((ext_vector_type(8)));
typedef float f32x4 __attribute__((ext_vector_type(4)));
typedef unsigned short u16x8 __attribute__((ext_vector_type(8)));

__device__ inline unsigned short f2h(float f) {
    return __half_as_ushort(__float2half(f));
}
__device__ inline float h2f(unsigned short u) {
    return __half2float(__ushort_as_half(u));
}

// ---------------------------------------------------------------------------
// Convert x (fp32) -> fp16
// ---------------------------------------------------------------------------
__global__ void convert_x(const float* __restrict__ x, ushort* __restrict__ xh) {
    int i = (blockIdx.x * blockDim.x + threadIdx.x) * 4;
    if (i < ND) {
        float4 v = *(const float4*)(x + i);
        *(ushort4*)(xh + i) = make_ushort4(f2h(v.x), f2h(v.y), f2h(v.z), f2h(v.w));
    }
}

// ---------------------------------------------------------------------------
// Pack 7 weight matrices [128x128] fp32 into exact fp16 MFMA B-fragment
// pairs: hi = fp16(W), lo = fp16((W - hi) * 2048)  (scaled into fp16 normal
// range; consumer applies accH + accL/2048).
// p = c*2048 + kc*512 + lane*8 + j holds W[kc*32+(lane>>4)*8+j][c*16+(lane&15)]
// matrices: 0-2 = W1s, 3-5 = W2s, 6 = Wp
// ---------------------------------------------------------------------------
__global__ void pack_w_split(const float* __restrict__ W1s, const float* __restrict__ W2s,
                             const float* __restrict__ Wp, ushort* __restrict__ out) {
    int idx = blockIdx.x * blockDim.x + threadIdx.x;
    if (idx >= 7 * 16384) return;
    int m = idx >> 14;
    int p = idx & 16383;
    int c = p >> 11;
    int kc = (p >> 9) & 3;
    int lane = (p >> 3) & 63;
    int j = p & 7;
    int k = kc * 32 + (lane >> 4) * 8 + j;
    int col = c * 16 + (lane & 15);
    const float* src = (m < 3) ? (W1s + (size_t)m * 16384)
                     : (m < 6) ? (W2s + (size_t)(m - 3) * 16384)
                               : Wp;
    float v = src[k * 128 + col];
    unsigned short hi = f2h(v);
    float r = (v - h2f(hi)) * LO_SCALE;
    out[(size_t)(2 * m) * 16384 + p] = hi;
    out[(size_t)(2 * m + 1) * 16384 + p] = f2h(r);
}

// ---------------------------------------------------------------------------
// CSR build step 1: histogram of dst into offs[1..N]
// ---------------------------------------------------------------------------
__global__ void hist_kernel(const int* __restrict__ dst, int* __restrict__ offs) {
    int e = blockIdx.x * blockDim.x + threadIdx.x;
    if (e < N_EDGES) atomicAdd(&offs[dst[e] + 1], 1);
}

// ---------------------------------------------------------------------------
// CSR build step 2: in-place inclusive scan over offs[1..N], 8 elts/thread,
// also emits cursor[i] = offs[i] for i in [0, N).
// ---------------------------------------------------------------------------
__global__ void scan_kernel(int* __restrict__ offs, int* __restrict__ cursor) {
    __shared__ int wsum[16];
    __shared__ int carry_s;
    int tid = threadIdx.x;
    int lane = tid & 63;
    int wave = tid >> 6;
    if (tid == 0) { carry_s = 0; cursor[0] = 0; }
    __syncthreads();
    for (int base = 1; base <= N_NODES; base += 8192) {
        int i0 = base + tid * 8;
        int v[8];
        #pragma unroll
        for (int k = 0; k < 8; ++k) {
            int idx = i0 + k;
            v[k] = (idx <= N_NODES) ? offs[idx] : 0;
        }
        #pragma unroll
        for (int k = 1; k < 8; ++k) v[k] += v[k - 1];
        int tsum = v[7];
        int x = tsum;
        #pragma unroll
        for (int d = 1; d < 64; d <<= 1) {
            int y = __shfl_up(x, d, 64);
            if (lane >= d) x += y;
        }
        if (lane == 63) wsum[wave] = x;
        __syncthreads();
        if (wave == 0 && lane < 16) {
            int y = wsum[lane];
            #pragma unroll
            for (int d = 1; d < 16; d <<= 1) {
                int t = __shfl_up(y, d, 64);
                if (lane >= d) y += t;
            }
            wsum[lane] = y;
        }
        __syncthreads();
        int waveoff = (wave > 0) ? wsum[wave - 1] : 0;
        int total = wsum[15];
        int add = (x - tsum) + waveoff + carry_s;
        #pragma unroll
        for (int k = 0; k < 8; ++k) {
            int idx = i0 + k;
            if (idx <= N_NODES) {
                int val = v[k] + add;
                offs[idx] = val;
                if (idx < N_NODES) cursor[idx] = val;
            }
        }
        __syncthreads();
        if (tid == 0) carry_s += total;
        __syncthreads();
    }
}

// ---------------------------------------------------------------------------
// CSR build step 3: bucket-fill interleaved (src, weight) payload by dst.
// ---------------------------------------------------------------------------
__global__ void fill_kernel(const int* __restrict__ src, const int* __restrict__ dst,
                            const float* __restrict__ ew,
                            int* __restrict__ cursor, uint2* __restrict__ pay) {
    int e = blockIdx.x * blockDim.x + threadIdx.x;
    if (e < N_EDGES) {
        int d = dst[e];
        int p = atomicAdd(&cursor[d], 1);
        pay[p] = make_uint2((unsigned)src[e], __float_as_uint(ew[e]));
    }
}

// ---------------------------------------------------------------------------
// Gather-aggregate + GIN combine (fp16 in, fp32 accumulate, fp16 out):
// A[n] = fp16( (1+eps)*z[n] + sum_j w_j * z[src_j] )
// One node per 32-lane group, 4 features/lane, edge loop unrolled x4.
// ---------------------------------------------------------------------------
__global__ void gather_agg_f16(const ushort* __restrict__ z, const int* __restrict__ offs,
                               const uint2* __restrict__ pay,
                               const float* __restrict__ epsp, int layer,
                               ushort* __restrict__ A) {
    int tid = blockIdx.x * blockDim.x + threadIdx.x;
    int n = tid >> 5;
    if (n >= N_NODES) return;
    int f = (tid & 31) << 2;
    float epsv = 1.0f + epsp[layer];
    int beg = offs[n], end = offs[n + 1];
    ushort4 zi = *(const ushort4*)(z + (size_t)n * D + f);
    float ax = epsv * h2f(zi.x), ay = epsv * h2f(zi.y);
    float az = epsv * h2f(zi.z), aw = epsv * h2f(zi.w);
    int j = beg;
    for (; j + 4 <= end; j += 4) {
        uint2 e0 = pay[j];
        uint2 e1 = pay[j + 1];
        uint2 e2 = pay[j + 2];
        uint2 e3 = pay[j + 3];
        ushort4 v0 = *(const ushort4*)(z + (size_t)e0.x * D + f);
        ushort4 v1 = *(const ushort4*)(z + (size_t)e1.x * D + f);
        ushort4 v2 = *(const ushort4*)(z + (size_t)e2.x * D + f);
        ushort4 v3 = *(const ushort4*)(z + (size_t)e3.x * D + f);
        float w0 = __uint_as_float(e0.y);
        float w1 = __uint_as_float(e1.y);
        float w2 = __uint_as_float(e2.y);
        float w3 = __uint_as_float(e3.y);
        ax += h2f(v0.x) * w0 + h2f(v1.x) * w1 + h2f(v2.x) * w2 + h2f(v3.x) * w3;
        ay += h2f(v0.y) * w0 + h2f(v1.y) * w1 + h2f(v2.y) * w2 + h2f(v3.y) * w3;
        az += h2f(v0.z) * w0 + h2f(v1.z) * w1 + h2f(v2.z) * w2 + h2f(v3.z) * w3;
        aw += h2f(v0.w) * w0 + h2f(v1.w) * w1 + h2f(v2.w) * w2 + h2f(v3.w) * w3;
    }
    for (; j < end; ++j) {
        uint2 e0 = pay[j];
        ushort4 v0 = *(const ushort4*)(z + (size_t)e0.x * D + f);
        float w0 = __uint_as_float(e0.y);
        ax += h2f(v0.x) * w0; ay += h2f(v0.y) * w0;
        az += h2f(v0.z) * w0; aw += h2f(v0.w) * w0;
    }
    *(ushort4*)(A + (size_t)n * D + f) = make_ushort4(f2h(ax), f2h(ay), f2h(az), f2h(aw));
}

// ---------------------------------------------------------------------------
// Fused GIN MLP, direct fp16 MFMA with exact fp16-pair weights:
// Z = relu(relu(A@W1+b1)@W2+b2);  A@W = A@Whi + (A@Wlo)/2048  (A exact fp16).
// 64 rows/block, 4 waves x 16 rows. H tile is wave-private fp16 LDS -> no
// barriers needed except before the cross-wave STATS reduction.
// STATS: accumulate per-column sum / sum-of-squares of the fp16 Z values.
// ---------------------------------------------------------------------------
#define HSH 136   // ushorts: 128 + 8 pad (272B row stride, 16B aligned)
template<bool STATS>
__global__ __launch_bounds__(256) void mlp_fused(
    const ushort* __restrict__ A,
    const ushort* __restrict__ W1hi, const ushort* __restrict__ W1lo,
    const float* __restrict__ b1,
    const ushort* __restrict__ W2hi, const ushort* __restrict__ W2lo,
    const float* __restrict__ b2, ushort* __restrict__ Z,
    float* __restrict__ stats) {
    __shared__ ushort Hs[4][16 * HSH];
    __shared__ float red[256];
    int tid = threadIdx.x;
    int lane = tid & 63;
    int wave = tid >> 6;
    int rlo = lane & 15;
    int quad = lane >> 4;
    int blk0 = blockIdx.x * 64;
    int row0 = blk0 + wave * 16;
    int arow = row0 + rlo;
    int ar = (arow < N_NODES) ? arow : (N_NODES - 1);

    const f16x8* W1h = (const f16x8*)W1hi;
    const f16x8* W1l = (const f16x8*)W1lo;
    const f16x8* W2h = (const f16x8*)W2hi;
    const f16x8* W2l = (const f16x8*)W2lo;

    // A fragments: raw fp16 loads, zero conversion
    f16x8 a[4];
    #pragma unroll
    for (int kc = 0; kc < 4; ++kc)
        a[kc] = *(const f16x8*)(A + (size_t)ar * D + kc * 32 + quad * 8);

    // GEMM1: hi + scaled-lo accumulators
    f32x4 accH[8], accL[8];
    #pragma unroll
    for (int c = 0; c < 8; ++c) { accH[c] = (f32x4){0.f,0.f,0.f,0.f}; accL[c] = (f32x4){0.f,0.f,0.f,0.f}; }
    #pragma unroll
    for (int c = 0; c < 8; ++c) {
        #pragma unroll
        for (int kc = 0; kc < 4; ++kc) {
            accH[c] = __builtin_amdgcn_mfma_f32_16x16x32_f16(a[kc], W1h[(c * 4 + kc) * 64 + lane], accH[c], 0, 0, 0);
            accL[c] = __builtin_amdgcn_mfma_f32_16x16x32_f16(a[kc], W1l[(c * 4 + kc) * 64 + lane], accL[c], 0, 0, 0);
        }
    }

    // epilogue 1: relu(hi + lo/2048 + b1) -> fp16 LDS (wave-private: no barrier)
    #pragma unroll
    for (int c = 0; c < 8; ++c) {
        int col = c * 16 + rlo;
        float bb = b1[col];
        #pragma unroll
        for (int r = 0; r < 4; ++r) {
            float h = fmaxf(accH[c][r] + accL[c][r] * LO_INV + bb, 0.f);
            Hs[wave][(quad * 4 + r) * HSH + col] = f2h(h);
        }
    }

    // A2 fragments: raw fp16 LDS loads
    f16x8 a2[4];
    #pragma unroll
    for (int kc = 0; kc < 4; ++kc)
        a2[kc] = *(const f16x8*)&Hs[wave][rlo * HSH + kc * 32 + quad * 8];

    // GEMM2
    f32x4 acc2H[8], acc2L[8];
    #pragma unroll
    for (int c = 0; c < 8; ++c) { acc2H[c] = (f32x4){0.f,0.f,0.f,0.f}; acc2L[c] = (f32x4){0.f,0.f,0.f,0.f}; }
    #pragma unroll
    for (int c = 0; c < 8; ++c) {
        #pragma unroll
        for (int kc = 0; kc < 4; ++kc) {
            acc2H[c] = __builtin_amdgcn_mfma_f32_16x16x32_f16(a2[kc], W2h[(c * 4 + kc) * 64 + lane], acc2H[c], 0, 0, 0);
            acc2L[c] = __builtin_amdgcn_mfma_f32_16x16x32_f16(a2[kc], W2l[(c * 4 + kc) * 64 + lane], acc2L[c], 0, 0, 0);
        }
    }

    // epilogue 2: relu(hi + lo/2048 + b2) -> fp16 LDS (wave-private)
    #pragma unroll
    for (int c = 0; c < 8; ++c) {
        int col = c * 16 + rlo;
        float bb = b2[col];
        #pragma unroll
        for (int r = 0; r < 4; ++r) {
            float z = fmaxf(acc2H[c][r] + acc2L[c][r] * LO_INV + bb, 0.f);
            Hs[wave][(quad * 4 + r) * HSH + col] = f2h(z);
        }
    }

    // coalesced copy-out: already fp16, straight 16B copies (wave-private)
    #pragma unroll
    for (int p2 = 0; p2 < 4; ++p2) {
        int r = p2 * 4 + quad;
        int grow = row0 + r;
        if (grow < N_NODES) {
            *(float4*)(Z + (size_t)grow * D + rlo * 8) =
                *(const float4*)&Hs[wave][r * HSH + rlo * 8];
        }
    }

    if (STATS) {
        __syncthreads();   // cross-wave read of all four H tiles
        int col = tid & 127;
        int half = tid >> 7;
        float s = 0.f, s2 = 0.f;
        #pragma unroll
        for (int i = 0; i < 32; ++i) {
            int row = half * 32 + i;
            if (blk0 + row < N_NODES) {
                float v = h2f(Hs[row >> 4][(row & 15) * HSH + col]);
                s += v;
                s2 += v * v;
            }
        }
        red[tid] = s;
        __syncthreads();
        if (half == 0) atomicAdd(&stats[col], s + red[tid + 128]);
        __syncthreads();
        red[tid] = s2;
        __syncthreads();
        if (half == 0) atomicAdd(&stats[D + col], s2 + red[tid + 128]);
    }
}

// ---------------------------------------------------------------------------
// Final: zn = BN(Z)*gamma+beta (fp32 out), p = PReLU(zn @ Wp + bp) (fp32 out)
// fp16 MFMA with exact fp16-pair Wp; zn rounded to fp16 only for the GEMM.
// ---------------------------------------------------------------------------
#define PSTR 132   // floats
__global__ __launch_bounds__(256) void bn_proj(
    const ushort* __restrict__ Z, const float* __restrict__ stats,
    const float* __restrict__ gamma, const float* __restrict__ beta,
    const ushort* __restrict__ Wphi, const ushort* __restrict__ Wplo,
    const float* __restrict__ bp, const float* __restrict__ prelu_a,
    float* __restrict__ zn_out, float* __restrict__ p_out) {
    __shared__ float sc_s[D];
    __shared__ float sh_s[D];
    __shared__ float Ps[4][16 * PSTR];
    int tid = threadIdx.x;
    int lane = tid & 63;
    int wave = tid >> 6;
    int rlo = lane & 15;
    int quad = lane >> 4;

    if (tid < D) {
        float m = stats[tid] * (1.0f / N_NODES);
        float v = stats[D + tid] * (1.0f / N_NODES) - m * m;
        float rs = rsqrtf(v + BN_EPS);
        float sc = rs * gamma[tid];
        sc_s[tid] = sc;
        sh_s[tid] = beta[tid] - m * sc;
    }
    __syncthreads();

    int row0 = blockIdx.x * 64 + wave * 16;
    int arow = row0 + rlo;
    int ar = (arow < N_NODES) ? arow : (N_NODES - 1);

    const f16x8* Wh = (const f16x8*)Wphi;
    const f16x8* Wl = (const f16x8*)Wplo;

    // load Z frags, apply BN -> zn (fp32 store + fp16 a-frags)
    f16x8 a[4];
    #pragma unroll
    for (int kc = 0; kc < 4; ++kc) {
        u16x8 raw = *(const u16x8*)(Z + (size_t)ar * D + kc * 32 + quad * 8);
        float zn[8];
        #pragma unroll
        for (int j = 0; j < 8; ++j) {
            int k = kc * 32 + quad * 8 + j;
            zn[j] = sc_s[k] * h2f(raw[j]) + sh_s[k];
            a[kc][j] = (_Float16)zn[j];
        }
        if (arow < N_NODES) {
            float* dst = zn_out + (size_t)arow * D + kc * 32 + quad * 8;
            *(float4*)dst = make_float4(zn[0], zn[1], zn[2], zn[3]);
            *(float4*)(dst + 4) = make_float4(zn[4], zn[5], zn[6], zn[7]);
        }
    }

    f32x4 accH[8], accL[8];
    #pragma unroll
    for (int c = 0; c < 8; ++c) { accH[c] = (f32x4){0.f,0.f,0.f,0.f}; accL[c] = (f32x4){0.f,0.f,0.f,0.f}; }
    #pragma unroll
    for (int c = 0; c < 8; ++c) {
        #pragma unroll
        for (int kc = 0; kc < 4; ++kc) {
            accH[c] = __builtin_amdgcn_mfma_f32_16x16x32_f16(a[kc], Wh[(c * 4 + kc) * 64 + lane], accH[c], 0, 0, 0);
            accL[c] = __builtin_amdgcn_mfma_f32_16x16x32_f16(a[kc], Wl[(c * 4 + kc) * 64 + lane], accL[c], 0, 0, 0);
        }
    }

    float aP = prelu_a[0];
    #pragma unroll
    for (int c = 0; c < 8; ++c) {
        int col = c * 16 + rlo;
        float bb = bp[col];
        #pragma unroll
        for (int r = 0; r < 4; ++r) {
            float v = accH[c][r] + accL[c][r] * LO_INV + bb;
            v = (v >= 0.f) ? v : aP * v;
            Ps[wave][(quad * 4 + r) * PSTR + col] = v;
        }
    }
    // Ps tile is wave-private: no barrier needed before the coalesced store
    #pragma unroll
    for (int p2 = 0; p2 < 8; ++p2) {
        int r = p2 * 2 + (lane >> 5);
        int grow = row0 + r;
        if (grow < N_NODES) {
            *(float4*)(p_out + (size_t)grow * D + (lane & 31) * 4) =
                *(const float4*)&Ps[wave][r * PSTR + (lane & 31) * 4];
        }
    }
}

// ---------------------------------------------------------------------------
extern "C" void kernel_launch(void* const* d_in, const int* in_sizes, int n_in,
                              void* d_out, int out_size, void* d_ws, size_t ws_size,
                              hipStream_t stream) {
    (void)in_sizes; (void)n_in; (void)out_size; (void)ws_size;
    const float* x     = (const float*)d_in[0];
    const float* ew    = (const float*)d_in[1];
    const float* W1s   = (const float*)d_in[2];
    const float* b1s   = (const float*)d_in[3];
    const float* W2s   = (const float*)d_in[4];
    const float* b2s   = (const float*)d_in[5];
    const float* eps   = (const float*)d_in[6];
    const float* gamma = (const float*)d_in[7];
    const float* beta  = (const float*)d_in[8];
    const float* Wp    = (const float*)d_in[9];
    const float* bp    = (const float*)d_in[10];
    const float* pa    = (const float*)d_in[11];
    const int*   ei    = (const int*)d_in[12];
    const int* srcp = ei;
    const int* dstp = ei + N_EDGES;

    // workspace layout (bytes):
    char* wsb = (char*)d_ws;
    float*  stats  = (float*)wsb;                 wsb += 1024;           // 256 f
    int*    offs   = (int*)wsb;                   wsb += 200016;         // 50004 i
    int*    cursor = (int*)wsb;                   wsb += 200016;         // 50004 i
    uint2*  pay    = (uint2*)wsb;                 wsb += 6400000;        // 800000 uint2
    ushort* Wpk    = (ushort*)wsb;                wsb += 14 * 16384 * 2; // fp16-pair weights
    ushort* Xh     = (ushort*)wsb;                wsb += (size_t)ND * 2; // x in fp16
    ushort* Ah     = (ushort*)wsb;                wsb += (size_t)ND * 2; // gather out fp16
    ushort* Zh     = (ushort*)wsb;                wsb += (size_t)ND * 2; // layer out fp16

    float* out_zn = (float*)d_out;
    float* out_p  = out_zn + ND;

    hipMemsetAsync(stats, 0, 256 * sizeof(float), stream);
    hipMemsetAsync(offs, 0, (N_NODES + 1) * sizeof(int), stream);

    convert_x<<<(ND / 4 + 255) / 256, 256, 0, stream>>>(x, Xh);
    pack_w_split<<<(7 * 16384 + 255) / 256, 256, 0, stream>>>(W1s, W2s, Wp, Wpk);

    hist_kernel<<<(N_EDGES + 255) / 256, 256, 0, stream>>>(dstp, offs);
    scan_kernel<<<1, 1024, 0, stream>>>(offs, cursor);
    fill_kernel<<<(N_EDGES + 255) / 256, 256, 0, stream>>>(srcp, dstp, ew, cursor, pay);

    int mgrid = (N_NODES + 63) / 64;
    const ushort* zin = Xh;
    for (int l = 0; l < 3; ++l) {
        gather_agg_f16<<<(N_NODES * 32 + 255) / 256, 256, 0, stream>>>(zin, offs, pay, eps, l, Ah);
        if (l < 2) {
            mlp_fused<false><<<mgrid, 256, 0, stream>>>(Ah,
                Wpk + (size_t)(2 * l) * 16384,       Wpk + (size_t)(2 * l + 1) * 16384, b1s + (size_t)l * D,
                Wpk + (size_t)(2 * (3 + l)) * 16384, Wpk + (size_t)(2 * (3 + l) + 1) * 16384, b2s + (size_t)l * D,
                Zh, stats);
        } else {
            mlp_fused<true><<<mgrid, 256, 0, stream>>>(Ah,
                Wpk + (size_t)(2 * l) * 16384,       Wpk + (size_t)(2 * l + 1) * 16384, b1s + (size_t)l * D,
                Wpk + (size_t)(2 * (3 + l)) * 16384, Wpk + (size_t)(2 * (3 + l) + 1) * 16384, b2s + (size_t)l * D,
                Zh, stats);
        }
        zin = Zh;
    }
    bn_proj<<<mgrid, 256, 0, stream>>>(Zh, stats, gamma, beta,
        Wpk + (size_t)12 * 16384, Wpk + (size_t)13 * 16384, bp, pa, out_zn, out_p);
}

// Round 12
// 445.953 us; speedup vs baseline: 1.0825x; 1.0825x over previous
//
#include <hip/hip_runtime.h>
#include <hip/hip_fp16.h>

#define N_NODES 50000
#define N_EDGES 800000
#define D 128
#define ND (N_NODES * D)
#define BN_EPS 1e-5f

typedef short bf16x8 __attribute__((ext_vector_type(8)));
typedef float f32x4 __attribute__((ext_vector_type(4)));
typedef unsigned short u16x8 __attribute__((ext_vector_type(8)));

__device__ inline unsigned short f2bf(float f) {
    unsigned int u = __float_as_uint(f);
    u += 0x7FFF + ((u >> 16) & 1);
    return (unsigned short)(u >> 16);
}
__device__ inline float bf2f(unsigned short h) {
    return __uint_as_float(((unsigned int)h) << 16);
}
__device__ inline unsigned short f2h(float f) {
    return __half_as_ushort(__float2half(f));
}
__device__ inline float h2f(unsigned short u) {
    return __half2float(__ushort_as_half(u));
}

// ---------------------------------------------------------------------------
// Convert x (fp32) -> fp16
// ---------------------------------------------------------------------------
__global__ void convert_x(const float* __restrict__ x, ushort* __restrict__ xh) {
    int i = (blockIdx.x * blockDim.x + threadIdx.x) * 4;
    if (i < ND) {
        float4 v = *(const float4*)(x + i);
        *(ushort4*)(xh + i) = make_ushort4(f2h(v.x), f2h(v.y), f2h(v.z), f2h(v.w));
    }
}

// ---------------------------------------------------------------------------
// Pack 7 weight matrices [128x128] fp32 into split-bf16 MFMA B-fragment pairs.
// (round-10 version — split-bf16 is empirically the best MLP operating point:
//  the conversion VALU work overlaps the latency-bound weight/A loads)
// ---------------------------------------------------------------------------
__global__ void pack_w_split(const float* __restrict__ W1s, const float* __restrict__ W2s,
                             const float* __restrict__ Wp, ushort* __restrict__ out) {
    int idx = blockIdx.x * blockDim.x + threadIdx.x;
    if (idx >= 7 * 16384) return;
    int m = idx >> 14;
    int p = idx & 16383;
    int c = p >> 11;
    int kc = (p >> 9) & 3;
    int lane = (p >> 3) & 63;
    int j = p & 7;
    int k = kc * 32 + (lane >> 4) * 8 + j;
    int col = c * 16 + (lane & 15);
    const float* src = (m < 3) ? (W1s + (size_t)m * 16384)
                     : (m < 6) ? (W2s + (size_t)(m - 3) * 16384)
                               : Wp;
    float v = src[k * 128 + col];
    unsigned short hi = f2bf(v);
    float r = v - bf2f(hi);
    out[(size_t)(2 * m) * 16384 + p] = hi;
    out[(size_t)(2 * m + 1) * 16384 + p] = f2bf(r);
}

// ---------------------------------------------------------------------------
// CSR build step 1: histogram of dst into offs[1..N]
// ---------------------------------------------------------------------------
__global__ void hist_kernel(const int* __restrict__ dst, int* __restrict__ offs) {
    int e = blockIdx.x * blockDim.x + threadIdx.x;
    if (e < N_EDGES) atomicAdd(&offs[dst[e] + 1], 1);
}

// ---------------------------------------------------------------------------
// CSR build step 2: in-place inclusive scan over offs[1..N], 8 elts/thread,
// also emits cursor[i] = offs[i] for i in [0, N).
// ---------------------------------------------------------------------------
__global__ void scan_kernel(int* __restrict__ offs, int* __restrict__ cursor) {
    __shared__ int wsum[16];
    __shared__ int carry_s;
    int tid = threadIdx.x;
    int lane = tid & 63;
    int wave = tid >> 6;
    if (tid == 0) { carry_s = 0; cursor[0] = 0; }
    __syncthreads();
    for (int base = 1; base <= N_NODES; base += 8192) {
        int i0 = base + tid * 8;
        int v[8];
        #pragma unroll
        for (int k = 0; k < 8; ++k) {
            int idx = i0 + k;
            v[k] = (idx <= N_NODES) ? offs[idx] : 0;
        }
        #pragma unroll
        for (int k = 1; k < 8; ++k) v[k] += v[k - 1];
        int tsum = v[7];
        int x = tsum;
        #pragma unroll
        for (int d = 1; d < 64; d <<= 1) {
            int y = __shfl_up(x, d, 64);
            if (lane >= d) x += y;
        }
        if (lane == 63) wsum[wave] = x;
        __syncthreads();
        if (wave == 0 && lane < 16) {
            int y = wsum[lane];
            #pragma unroll
            for (int d = 1; d < 16; d <<= 1) {
                int t = __shfl_up(y, d, 64);
                if (lane >= d) y += t;
            }
            wsum[lane] = y;
        }
        __syncthreads();
        int waveoff = (wave > 0) ? wsum[wave - 1] : 0;
        int total = wsum[15];
        int add = (x - tsum) + waveoff + carry_s;
        #pragma unroll
        for (int k = 0; k < 8; ++k) {
            int idx = i0 + k;
            if (idx <= N_NODES) {
                int val = v[k] + add;
                offs[idx] = val;
                if (idx < N_NODES) cursor[idx] = val;
            }
        }
        __syncthreads();
        if (tid == 0) carry_s += total;
        __syncthreads();
    }
}

// ---------------------------------------------------------------------------
// CSR build step 3: bucket-fill COMPRESSED payload by dst.
// src fits in 16 bits (N_NODES=50000 < 65536); weight as fp16.
// 4B per edge: half the dirty-line scatter traffic of the 8B payload.
// ---------------------------------------------------------------------------
__global__ void fill_kernel(const int* __restrict__ src, const int* __restrict__ dst,
                            const float* __restrict__ ew,
                            int* __restrict__ cursor, unsigned* __restrict__ pay) {
    int e = blockIdx.x * blockDim.x + threadIdx.x;
    if (e < N_EDGES) {
        int d = dst[e];
        int p = atomicAdd(&cursor[d], 1);
        pay[p] = (unsigned)src[e] | ((unsigned)f2h(ew[e]) << 16);
    }
}

// ---------------------------------------------------------------------------
// Gather-aggregate + GIN combine (fp16 in, fp32 accumulate, fp16 out):
// A[n] = fp16( (1+eps)*z[n] + sum_j w_j * z[src_j] )
// One node per 32-lane group, 4 features/lane, edge loop unrolled x4.
// ---------------------------------------------------------------------------
__global__ void gather_agg_f16(const ushort* __restrict__ z, const int* __restrict__ offs,
                               const unsigned* __restrict__ pay,
                               const float* __restrict__ epsp, int layer,
                               ushort* __restrict__ A) {
    int tid = blockIdx.x * blockDim.x + threadIdx.x;
    int n = tid >> 5;
    if (n >= N_NODES) return;
    int f = (tid & 31) << 2;
    float epsv = 1.0f + epsp[layer];
    int beg = offs[n], end = offs[n + 1];
    ushort4 zi = *(const ushort4*)(z + (size_t)n * D + f);
    float ax = epsv * h2f(zi.x), ay = epsv * h2f(zi.y);
    float az = epsv * h2f(zi.z), aw = epsv * h2f(zi.w);
    int j = beg;
    for (; j + 4 <= end; j += 4) {
        unsigned e0 = pay[j];
        unsigned e1 = pay[j + 1];
        unsigned e2 = pay[j + 2];
        unsigned e3 = pay[j + 3];
        ushort4 v0 = *(const ushort4*)(z + (size_t)(e0 & 0xFFFF) * D + f);
        ushort4 v1 = *(const ushort4*)(z + (size_t)(e1 & 0xFFFF) * D + f);
        ushort4 v2 = *(const ushort4*)(z + (size_t)(e2 & 0xFFFF) * D + f);
        ushort4 v3 = *(const ushort4*)(z + (size_t)(e3 & 0xFFFF) * D + f);
        float w0 = h2f((unsigned short)(e0 >> 16));
        float w1 = h2f((unsigned short)(e1 >> 16));
        float w2 = h2f((unsigned short)(e2 >> 16));
        float w3 = h2f((unsigned short)(e3 >> 16));
        ax += h2f(v0.x) * w0 + h2f(v1.x) * w1 + h2f(v2.x) * w2 + h2f(v3.x) * w3;
        ay += h2f(v0.y) * w0 + h2f(v1.y) * w1 + h2f(v2.y) * w2 + h2f(v3.y) * w3;
        az += h2f(v0.z) * w0 + h2f(v1.z) * w1 + h2f(v2.z) * w2 + h2f(v3.z) * w3;
        aw += h2f(v0.w) * w0 + h2f(v1.w) * w1 + h2f(v2.w) * w2 + h2f(v3.w) * w3;
    }
    for (; j < end; ++j) {
        unsigned e0 = pay[j];
        ushort4 v0 = *(const ushort4*)(z + (size_t)(e0 & 0xFFFF) * D + f);
        float w0 = h2f((unsigned short)(e0 >> 16));
        ax += h2f(v0.x) * w0; ay += h2f(v0.y) * w0;
        az += h2f(v0.z) * w0; aw += h2f(v0.w) * w0;
    }
    *(ushort4*)(A + (size_t)n * D + f) = make_ushort4(f2h(ax), f2h(ay), f2h(az), f2h(aw));
}

// ---------------------------------------------------------------------------
// Fused GIN MLP, split-bf16 MFMA (fp16 in/out, ~fp32 GEMM accuracy):
// Z = relu(relu(A@W1+b1)@W2+b2); 64 rows/block, 4 waves x 16 rows.
// (round-10 version — conversion VALU overlaps latency-bound loads)
// STATS: accumulate per-column sum / sum-of-squares (fp32 pre-rounding).
// ---------------------------------------------------------------------------
#define HSTR 132   // floats: 128 + 4 pad
template<bool STATS>
__global__ __launch_bounds__(256) void mlp_fused(
    const ushort* __restrict__ A,
    const ushort* __restrict__ W1hi, const ushort* __restrict__ W1lo,
    const float* __restrict__ b1,
    const ushort* __restrict__ W2hi, const ushort* __restrict__ W2lo,
    const float* __restrict__ b2, ushort* __restrict__ Z,
    float* __restrict__ stats) {
    __shared__ float Hs[4][16 * HSTR];
    __shared__ float red[256];
    int tid = threadIdx.x;
    int lane = tid & 63;
    int wave = tid >> 6;
    int rlo = lane & 15;
    int quad = lane >> 4;
    int blk0 = blockIdx.x * 64;
    int row0 = blk0 + wave * 16;
    int arow = row0 + rlo;
    int ar = (arow < N_NODES) ? arow : (N_NODES - 1);

    const bf16x8* W1h = (const bf16x8*)W1hi;
    const bf16x8* W1l = (const bf16x8*)W1lo;
    const bf16x8* W2h = (const bf16x8*)W2hi;
    const bf16x8* W2l = (const bf16x8*)W2lo;

    // A fragments from global fp16 (split): lane holds A[ar][kc*32 + quad*8 + j]
    bf16x8 ahi[4], alo[4];
    #pragma unroll
    for (int kc = 0; kc < 4; ++kc) {
        u16x8 raw = *(const u16x8*)(A + (size_t)ar * D + kc * 32 + quad * 8);
        #pragma unroll
        for (int j = 0; j < 8; ++j) {
            float v = h2f(raw[j]);
            unsigned short h = f2bf(v);
            ahi[kc][j] = (short)h;
            alo[kc][j] = (short)f2bf(v - bf2f(h));
        }
    }

    // GEMM1 (3-term split)
    f32x4 acc[8];
    #pragma unroll
    for (int c = 0; c < 8; ++c) acc[c] = (f32x4){0.f, 0.f, 0.f, 0.f};
    #pragma unroll
    for (int c = 0; c < 8; ++c) {
        #pragma unroll
        for (int kc = 0; kc < 4; ++kc) {
            bf16x8 wh = W1h[(c * 4 + kc) * 64 + lane];
            bf16x8 wl = W1l[(c * 4 + kc) * 64 + lane];
            acc[c] = __builtin_amdgcn_mfma_f32_16x16x32_bf16(alo[kc], wh, acc[c], 0, 0, 0);
            acc[c] = __builtin_amdgcn_mfma_f32_16x16x32_bf16(ahi[kc], wl, acc[c], 0, 0, 0);
            acc[c] = __builtin_amdgcn_mfma_f32_16x16x32_bf16(ahi[kc], wh, acc[c], 0, 0, 0);
        }
    }

    // epilogue 1: relu(acc + b1) -> LDS fp32 (C layout: row=quad*4+r, col=c*16+rlo)
    #pragma unroll
    for (int c = 0; c < 8; ++c) {
        int col = c * 16 + rlo;
        float bb = b1[col];
        #pragma unroll
        for (int r = 0; r < 4; ++r) {
            Hs[wave][(quad * 4 + r) * HSTR + col] = fmaxf(acc[c][r] + bb, 0.f);
        }
    }
    __syncthreads();

    // A2 fragments from LDS (split)
    bf16x8 a2hi[4], a2lo[4];
    #pragma unroll
    for (int kc = 0; kc < 4; ++kc) {
        const float* p = &Hs[wave][rlo * HSTR + kc * 32 + quad * 8];
        #pragma unroll
        for (int j = 0; j < 8; ++j) {
            float v = p[j];
            unsigned short h = f2bf(v);
            a2hi[kc][j] = (short)h;
            a2lo[kc][j] = (short)f2bf(v - bf2f(h));
        }
    }

    // GEMM2 (3-term split)
    f32x4 acc2[8];
    #pragma unroll
    for (int c = 0; c < 8; ++c) acc2[c] = (f32x4){0.f, 0.f, 0.f, 0.f};
    #pragma unroll
    for (int c = 0; c < 8; ++c) {
        #pragma unroll
        for (int kc = 0; kc < 4; ++kc) {
            bf16x8 wh = W2h[(c * 4 + kc) * 64 + lane];
            bf16x8 wl = W2l[(c * 4 + kc) * 64 + lane];
            acc2[c] = __builtin_amdgcn_mfma_f32_16x16x32_bf16(a2lo[kc], wh, acc2[c], 0, 0, 0);
            acc2[c] = __builtin_amdgcn_mfma_f32_16x16x32_bf16(a2hi[kc], wl, acc2[c], 0, 0, 0);
            acc2[c] = __builtin_amdgcn_mfma_f32_16x16x32_bf16(a2hi[kc], wh, acc2[c], 0, 0, 0);
        }
    }

    __syncthreads();
    // epilogue 2: relu(acc2 + b2) -> LDS, then coalesced fp16 copy-out
    #pragma unroll
    for (int c = 0; c < 8; ++c) {
        int col = c * 16 + rlo;
        float bb = b2[col];
        #pragma unroll
        for (int r = 0; r < 4; ++r) {
            Hs[wave][(quad * 4 + r) * HSTR + col] = fmaxf(acc2[c][r] + bb, 0.f);
        }
    }
    __syncthreads();
    #pragma unroll
    for (int p2 = 0; p2 < 4; ++p2) {
        int r = p2 * 4 + quad;
        int grow = row0 + r;
        if (grow < N_NODES) {
            float4 lo = *(const float4*)&Hs[wave][r * HSTR + rlo * 8];
            float4 hi = *(const float4*)&Hs[wave][r * HSTR + rlo * 8 + 4];
            ushort us[8] = {f2h(lo.x), f2h(lo.y), f2h(lo.z), f2h(lo.w),
                            f2h(hi.x), f2h(hi.y), f2h(hi.z), f2h(hi.w)};
            *(float4*)(Z + (size_t)grow * D + rlo * 8) = *(const float4*)us;
        }
    }

    if (STATS) {
        // per-block column reduction over the 64 rows in Hs (fp32 values)
        int col = tid & 127;
        int half = tid >> 7;
        float s = 0.f, s2 = 0.f;
        #pragma unroll
        for (int i = 0; i < 32; ++i) {
            int row = half * 32 + i;
            if (blk0 + row < N_NODES) {
                float v = Hs[row >> 4][(row & 15) * HSTR + col];
                s += v;
                s2 += v * v;
            }
        }
        red[tid] = s;
        __syncthreads();
        if (half == 0) atomicAdd(&stats[col], s + red[tid + 128]);
        __syncthreads();
        red[tid] = s2;
        __syncthreads();
        if (half == 0) atomicAdd(&stats[D + col], s2 + red[tid + 128]);
    }
}

// ---------------------------------------------------------------------------
// Final: zn = BN(Z)*gamma+beta (fp32 out), p = PReLU(zn @ Wp + bp) (fp32 out)
// Split-bf16 MFMA GEMM with BN folded into the fragment load. (round-10)
// ---------------------------------------------------------------------------
#define PSTR 132   // floats
__global__ __launch_bounds__(256) void bn_proj(
    const ushort* __restrict__ Z, const float* __restrict__ stats,
    const float* __restrict__ gamma, const float* __restrict__ beta,
    const ushort* __restrict__ Wphi, const ushort* __restrict__ Wplo,
    const float* __restrict__ bp, const float* __restrict__ prelu_a,
    float* __restrict__ zn_out, float* __restrict__ p_out) {
    __shared__ float sc_s[D];
    __shared__ float sh_s[D];
    __shared__ float Ps[4][16 * PSTR];
    int tid = threadIdx.x;
    int lane = tid & 63;
    int wave = tid >> 6;
    int rlo = lane & 15;
    int quad = lane >> 4;

    if (tid < D) {
        float m = stats[tid] * (1.0f / N_NODES);
        float v = stats[D + tid] * (1.0f / N_NODES) - m * m;
        float rs = rsqrtf(v + BN_EPS);
        float sc = rs * gamma[tid];
        sc_s[tid] = sc;
        sh_s[tid] = beta[tid] - m * sc;
    }
    __syncthreads();

    int row0 = blockIdx.x * 64 + wave * 16;
    int arow = row0 + rlo;
    int ar = (arow < N_NODES) ? arow : (N_NODES - 1);

    const bf16x8* Wh = (const bf16x8*)Wphi;
    const bf16x8* Wl = (const bf16x8*)Wplo;

    // load Z frags, apply BN -> zn (fp32 store + split-bf16 a-frags)
    bf16x8 ahi[4], alo[4];
    #pragma unroll
    for (int kc = 0; kc < 4; ++kc) {
        u16x8 raw = *(const u16x8*)(Z + (size_t)ar * D + kc * 32 + quad * 8);
        float zn[8];
        #pragma unroll
        for (int j = 0; j < 8; ++j) {
            int k = kc * 32 + quad * 8 + j;
            zn[j] = sc_s[k] * h2f(raw[j]) + sh_s[k];
            unsigned short h = f2bf(zn[j]);
            ahi[kc][j] = (short)h;
            alo[kc][j] = (short)f2bf(zn[j] - bf2f(h));
        }
        if (arow < N_NODES) {
            float* dst = zn_out + (size_t)arow * D + kc * 32 + quad * 8;
            *(float4*)dst = make_float4(zn[0], zn[1], zn[2], zn[3]);
            *(float4*)(dst + 4) = make_float4(zn[4], zn[5], zn[6], zn[7]);
        }
    }

    f32x4 acc[8];
    #pragma unroll
    for (int c = 0; c < 8; ++c) acc[c] = (f32x4){0.f, 0.f, 0.f, 0.f};
    #pragma unroll
    for (int c = 0; c < 8; ++c) {
        #pragma unroll
        for (int kc = 0; kc < 4; ++kc) {
            bf16x8 wh = Wh[(c * 4 + kc) * 64 + lane];
            bf16x8 wl = Wl[(c * 4 + kc) * 64 + lane];
            acc[c] = __builtin_amdgcn_mfma_f32_16x16x32_bf16(alo[kc], wh, acc[c], 0, 0, 0);
            acc[c] = __builtin_amdgcn_mfma_f32_16x16x32_bf16(ahi[kc], wl, acc[c], 0, 0, 0);
            acc[c] = __builtin_amdgcn_mfma_f32_16x16x32_bf16(ahi[kc], wh, acc[c], 0, 0, 0);
        }
    }

    float aP = prelu_a[0];
    #pragma unroll
    for (int c = 0; c < 8; ++c) {
        int col = c * 16 + rlo;
        float bb = bp[col];
        #pragma unroll
        for (int r = 0; r < 4; ++r) {
            float v = acc[c][r] + bb;
            v = (v >= 0.f) ? v : aP * v;
            Ps[wave][(quad * 4 + r) * PSTR + col] = v;
        }
    }
    __syncthreads();
    #pragma unroll
    for (int p2 = 0; p2 < 8; ++p2) {
        int r = p2 * 2 + (lane >> 5);
        int grow = row0 + r;
        if (grow < N_NODES) {
            *(float4*)(p_out + (size_t)grow * D + (lane & 31) * 4) =
                *(const float4*)&Ps[wave][r * PSTR + (lane & 31) * 4];
        }
    }
}

// ---------------------------------------------------------------------------
extern "C" void kernel_launch(void* const* d_in, const int* in_sizes, int n_in,
                              void* d_out, int out_size, void* d_ws, size_t ws_size,
                              hipStream_t stream) {
    (void)in_sizes; (void)n_in; (void)out_size; (void)ws_size;
    const float* x     = (const float*)d_in[0];
    const float* ew    = (const float*)d_in[1];
    const float* W1s   = (const float*)d_in[2];
    const float* b1s   = (const float*)d_in[3];
    const float* W2s   = (const float*)d_in[4];
    const float* b2s   = (const float*)d_in[5];
    const float* eps   = (const float*)d_in[6];
    const float* gamma = (const float*)d_in[7];
    const float* beta  = (const float*)d_in[8];
    const float* Wp    = (const float*)d_in[9];
    const float* bp    = (const float*)d_in[10];
    const float* pa    = (const float*)d_in[11];
    const int*   ei    = (const int*)d_in[12];
    const int* srcp = ei;
    const int* dstp = ei + N_EDGES;

    // workspace layout (bytes):
    char* wsb = (char*)d_ws;
    float*    stats  = (float*)wsb;               wsb += 1024;           // 256 f
    int*      offs   = (int*)wsb;                 wsb += 200016;         // 50004 i
    int*      cursor = (int*)wsb;                 wsb += 200016;         // 50004 i
    unsigned* pay    = (unsigned*)wsb;            wsb += 3200000;        // 800000 u32
    ushort*   Wpk    = (ushort*)wsb;              wsb += 14 * 16384 * 2; // split weights
    ushort*   Xh     = (ushort*)wsb;              wsb += (size_t)ND * 2; // x in fp16
    ushort*   Ah     = (ushort*)wsb;              wsb += (size_t)ND * 2; // gather out fp16
    ushort*   Zh     = (ushort*)wsb;              wsb += (size_t)ND * 2; // layer out fp16

    float* out_zn = (float*)d_out;
    float* out_p  = out_zn + ND;

    hipMemsetAsync(stats, 0, 256 * sizeof(float), stream);
    hipMemsetAsync(offs, 0, (N_NODES + 1) * sizeof(int), stream);

    convert_x<<<(ND / 4 + 255) / 256, 256, 0, stream>>>(x, Xh);
    pack_w_split<<<(7 * 16384 + 255) / 256, 256, 0, stream>>>(W1s, W2s, Wp, Wpk);

    hist_kernel<<<(N_EDGES + 255) / 256, 256, 0, stream>>>(dstp, offs);
    scan_kernel<<<1, 1024, 0, stream>>>(offs, cursor);
    fill_kernel<<<(N_EDGES + 255) / 256, 256, 0, stream>>>(srcp, dstp, ew, cursor, pay);

    int mgrid = (N_NODES + 63) / 64;
    const ushort* zin = Xh;
    for (int l = 0; l < 3; ++l) {
        gather_agg_f16<<<(N_NODES * 32 + 255) / 256, 256, 0, stream>>>(zin, offs, pay, eps, l, Ah);
        if (l < 2) {
            mlp_fused<false><<<mgrid, 256, 0, stream>>>(Ah,
                Wpk + (size_t)(2 * l) * 16384,       Wpk + (size_t)(2 * l + 1) * 16384, b1s + (size_t)l * D,
                Wpk + (size_t)(2 * (3 + l)) * 16384, Wpk + (size_t)(2 * (3 + l) + 1) * 16384, b2s + (size_t)l * D,
                Zh, stats);
        } else {
            mlp_fused<true><<<mgrid, 256, 0, stream>>>(Ah,
                Wpk + (size_t)(2 * l) * 16384,       Wpk + (size_t)(2 * l + 1) * 16384, b1s + (size_t)l * D,
                Wpk + (size_t)(2 * (3 + l)) * 16384, Wpk + (size_t)(2 * (3 + l) + 1) * 16384, b2s + (size_t)l * D,
                Zh, stats);
        }
        zin = Zh;
    }
    bn_proj<<<mgrid, 256, 0, stream>>>(Zh, stats, gamma, beta,
        Wpk + (size_t)12 * 16384, Wpk + (size_t)13 * 16384, bp, pa, out_zn, out_p);
}